// Round 4
// baseline (9831.606 us; speedup 1.0000x reference)
//
#include <hip/hip_runtime.h>
#include <hip/hip_bf16.h>

// GRU: B=32, T=16384, H=64, CIN=COUT=1.
// d_out = [ out (B*T floats) | states (B*T*H floats) ], fp32.
//
// R4: ONE WAVE per batch (32 blocks x 64 threads). Thread l computes all three
// gate rows (l, 64+l, 128+l) -> r,z,n never leave the thread:
//   - ZERO barriers in the scan loop (single wave, lockstep).
//   - no gate-exchange LDS round trip (R3 had 2 LDS round trips + s_barrier/step).
//   - states stored straight to global per step (fire-and-forget; no vmcnt drain
//     because there is no barrier to drain at).
//   - divisions replaced with v_rcp_f32 (R3 had 3 exact-div sequences ~40cyc each
//     on the serial path).
// Cost: 192 FMA/lane/step (384 cyc issue) vs 64 in R3 — but R3's barrier+LDS
// round trips cost more than the extra 256 cyc of FMA issue.

#define Bv   32
#define Tv   16384
#define Hv   64
#define XCH  1024     // x chunk (floats)

__device__ __forceinline__ float dot4(float acc, const float4 a, const float4 b) {
    return fmaf(a.x, b.x, fmaf(a.y, b.y, fmaf(a.z, b.z, fmaf(a.w, b.w, acc))));
}

__global__ __launch_bounds__(64, 1) void gru_scan(
    const float* __restrict__ x,      // [B,T]
    const float* __restrict__ W_ih,   // [192] (CIN=1)
    const float* __restrict__ W_hh,   // [192,64]
    const float* __restrict__ b_ih,   // [192]
    const float* __restrict__ b_hh,   // [192]
    float* __restrict__ states)       // [B,T,64]
{
    const int b = blockIdx.x;
    const int l = threadIdx.x;        // hidden unit 0..63

    __shared__ float xs[XCH];         // 4 KB x chunk
    __shared__ float hs[Hv];          // 256 B h broadcast buffer

    const float* xb = x + (size_t)b * Tv;
    float*       sp = states + (size_t)b * Tv * Hv + l;

    // W_hh rows l (r), 64+l (z), 128+l (n) -> 48 named float4 (192 VGPRs)
    const float4* Wr = reinterpret_cast<const float4*>(W_hh + (size_t)l * Hv);
    const float4* Wz = reinterpret_cast<const float4*>(W_hh + (size_t)(64 + l) * Hv);
    const float4* Wn = reinterpret_cast<const float4*>(W_hh + (size_t)(128 + l) * Hv);
    const float4 wr0=Wr[0],  wr1=Wr[1],  wr2=Wr[2],  wr3=Wr[3];
    const float4 wr4=Wr[4],  wr5=Wr[5],  wr6=Wr[6],  wr7=Wr[7];
    const float4 wr8=Wr[8],  wr9=Wr[9],  wr10=Wr[10], wr11=Wr[11];
    const float4 wr12=Wr[12], wr13=Wr[13], wr14=Wr[14], wr15=Wr[15];
    const float4 wz0=Wz[0],  wz1=Wz[1],  wz2=Wz[2],  wz3=Wz[3];
    const float4 wz4=Wz[4],  wz5=Wz[5],  wz6=Wz[6],  wz7=Wz[7];
    const float4 wz8=Wz[8],  wz9=Wz[9],  wz10=Wz[10], wz11=Wz[11];
    const float4 wz12=Wz[12], wz13=Wz[13], wz14=Wz[14], wz15=Wz[15];
    const float4 wn0=Wn[0],  wn1=Wn[1],  wn2=Wn[2],  wn3=Wn[3];
    const float4 wn4=Wn[4],  wn5=Wn[5],  wn6=Wn[6],  wn7=Wn[7];
    const float4 wn8=Wn[8],  wn9=Wn[9],  wn10=Wn[10], wn11=Wn[11];
    const float4 wn12=Wn[12], wn13=Wn[13], wn14=Wn[14], wn15=Wn[15];

    const float bhr = b_hh[l], bhz = b_hh[64 + l], bhn = b_hh[128 + l];
    const float wir = W_ih[l], wiz = W_ih[64 + l], win = W_ih[128 + l];
    const float bir = b_ih[l], biz = b_ih[64 + l], bin_ = b_ih[128 + l];

    hs[l] = 0.0f;
    float h_prev = 0.0f;

    for (int t = 0; t < Tv; ++t) {
        if ((t & (XCH - 1)) == 0) {   // refill x chunk; same-wave, no barrier
            for (int i = l; i < XCH; i += 64) xs[i] = xb[t + i];
        }
        const float xt  = xs[t & (XCH - 1)];
        const float ir  = fmaf(xt, wir, bir);
        const float iz  = fmaf(xt, wiz, biz);
        const float in_ = fmaf(xt, win, bin_);

        // ---- 3 dots of 64 against broadcast h; 6 rotating accumulators ----
        const float4* hv = reinterpret_cast<const float4*>(hs);
        float ar0 = bhr, az0 = bhz, an0 = bhn;
        float ar1 = 0.f, az1 = 0.f, an1 = 0.f;
        float4 h;
        h = hv[0];  ar0 = dot4(ar0, wr0,  h); az0 = dot4(az0, wz0,  h); an0 = dot4(an0, wn0,  h);
        h = hv[1];  ar1 = dot4(ar1, wr1,  h); az1 = dot4(az1, wz1,  h); an1 = dot4(an1, wn1,  h);
        h = hv[2];  ar0 = dot4(ar0, wr2,  h); az0 = dot4(az0, wz2,  h); an0 = dot4(an0, wn2,  h);
        h = hv[3];  ar1 = dot4(ar1, wr3,  h); az1 = dot4(az1, wz3,  h); an1 = dot4(an1, wn3,  h);
        h = hv[4];  ar0 = dot4(ar0, wr4,  h); az0 = dot4(az0, wz4,  h); an0 = dot4(an0, wn4,  h);
        h = hv[5];  ar1 = dot4(ar1, wr5,  h); az1 = dot4(az1, wz5,  h); an1 = dot4(an1, wn5,  h);
        h = hv[6];  ar0 = dot4(ar0, wr6,  h); az0 = dot4(az0, wz6,  h); an0 = dot4(an0, wn6,  h);
        h = hv[7];  ar1 = dot4(ar1, wr7,  h); az1 = dot4(az1, wz7,  h); an1 = dot4(an1, wn7,  h);
        h = hv[8];  ar0 = dot4(ar0, wr8,  h); az0 = dot4(az0, wz8,  h); an0 = dot4(an0, wn8,  h);
        h = hv[9];  ar1 = dot4(ar1, wr9,  h); az1 = dot4(az1, wz9,  h); an1 = dot4(an1, wn9,  h);
        h = hv[10]; ar0 = dot4(ar0, wr10, h); az0 = dot4(az0, wz10, h); an0 = dot4(an0, wn10, h);
        h = hv[11]; ar1 = dot4(ar1, wr11, h); az1 = dot4(az1, wz11, h); an1 = dot4(an1, wn11, h);
        h = hv[12]; ar0 = dot4(ar0, wr12, h); az0 = dot4(az0, wz12, h); an0 = dot4(an0, wn12, h);
        h = hv[13]; ar1 = dot4(ar1, wr13, h); az1 = dot4(az1, wz13, h); an1 = dot4(an1, wn13, h);
        h = hv[14]; ar0 = dot4(ar0, wr14, h); az0 = dot4(az0, wz14, h); an0 = dot4(an0, wn14, h);
        h = hv[15]; ar1 = dot4(ar1, wr15, h); az1 = dot4(az1, wz15, h); an1 = dot4(an1, wn15, h);

        const float vr = ir + (ar0 + ar1);
        const float vz = iz + (az0 + az1);
        const float gn = an0 + an1;

        // fast sigmoid/tanh via v_rcp_f32 (rel err ~1e-7, fine vs 0.1 threshold)
        const float r  = __builtin_amdgcn_rcpf(1.0f + __expf(-vr));
        const float z  = __builtin_amdgcn_rcpf(1.0f + __expf(-vz));
        const float a  = fmaf(r, gn, in_);
        const float nn = 1.0f - 2.0f * __builtin_amdgcn_rcpf(__expf(2.0f * a) + 1.0f);
        const float hn = fmaf(z, h_prev - nn, nn);     // (1-z)*n + z*h

        h_prev = hn;
        hs[l]  = hn;          // broadcast for next step (same wave, no barrier)
        *sp    = hn;          // fire-and-forget states store
        sp    += Hv;
    }
}

// out[i] = states[i,:] . W_out + b_out + x[i],  i in [0, B*T)
__global__ __launch_bounds__(256) void gru_head(
    const float* __restrict__ x,
    const float* __restrict__ states,
    const float* __restrict__ W_out,   // [64]
    const float* __restrict__ b_out,   // [1]
    float* __restrict__ out)
{
    __shared__ float wsm[Hv];
    if (threadIdx.x < Hv) wsm[threadIdx.x] = W_out[threadIdx.x];
    __syncthreads();

    const int i = blockIdx.x * blockDim.x + threadIdx.x;
    if (i >= Bv * Tv) return;

    const float4* s4 = reinterpret_cast<const float4*>(states + (size_t)i * Hv);
    float acc = 0.0f;
#pragma unroll
    for (int k = 0; k < Hv / 4; ++k) {
        const float4 v = s4[k];
        acc = fmaf(v.x, wsm[4*k+0], acc);
        acc = fmaf(v.y, wsm[4*k+1], acc);
        acc = fmaf(v.z, wsm[4*k+2], acc);
        acc = fmaf(v.w, wsm[4*k+3], acc);
    }
    out[i] = acc + b_out[0] + x[i];
}

extern "C" void kernel_launch(void* const* d_in, const int* in_sizes, int n_in,
                              void* d_out, int out_size, void* d_ws, size_t ws_size,
                              hipStream_t stream) {
    const float* x     = (const float*)d_in[0];   // [B,T,1]
    const float* W_ih  = (const float*)d_in[1];   // [192,1]
    const float* W_hh  = (const float*)d_in[2];   // [192,64]
    const float* b_ih  = (const float*)d_in[3];   // [192]
    const float* b_hh  = (const float*)d_in[4];   // [192]
    const float* W_out = (const float*)d_in[5];   // [1,64]
    const float* b_out = (const float*)d_in[6];   // [1]

    float* out    = (float*)d_out;                // [B*T]
    float* states = out + (size_t)Bv * Tv;        // [B*T*H]

    gru_scan<<<Bv, 64, 0, stream>>>(x, W_ih, W_hh, b_ih, b_hh, states);
    gru_head<<<(Bv * Tv + 255) / 256, 256, 0, stream>>>(x, states, W_out, b_out, out);
}